// Round 10
// baseline (81.602 us; speedup 1.0000x reference)
//
#include <hip/hip_runtime.h>
#include <stdint.h>

#define N 4096
#define D 512
#define BK 128            // fp8 bytes (=elems) per K-chunk
#define KITERS (D / BK)   // 4
#define WTM 32            // wave-tile rows
#define WTN 64            // wave-tile cols
#define NTW 4160          // wave-tiles covering the lower triangle (incl. diag)
#define GRID (NTW / 4)    // 1040 blocks x 4 waves

typedef float f32x4 __attribute__((ext_vector_type(4)));
typedef int   i32x8 __attribute__((ext_vector_type(8)));
typedef int   i32x4 __attribute__((ext_vector_type(4)));

// ---------------------------------------------------------------------------
// Kernel 1: fp32 -> fp8 e4m3 (OCP) conversion + fp32 row squared-norms.
// One wave per row: 512 elems / 64 lanes = 8 elems/lane (one 8B store).
// Norms are exact fp32; only the Gram term carries fp8 error.
// ---------------------------------------------------------------------------
__global__ __launch_bounds__(256) void prep_kernel(const float* __restrict__ x,
                                                   unsigned char* __restrict__ xq,
                                                   float* __restrict__ sq) {
    int row  = blockIdx.x * 4 + (threadIdx.x >> 6);
    int lane = threadIdx.x & 63;
    const float* xr = x + (size_t)row * D + lane * 8;
    float4 v0 = *reinterpret_cast<const float4*>(xr);
    float4 v1 = *reinterpret_cast<const float4*>(xr + 4);

    int w0 = __builtin_amdgcn_cvt_pk_fp8_f32(v0.x, v0.y, 0, false);
    w0     = __builtin_amdgcn_cvt_pk_fp8_f32(v0.z, v0.w, w0, true);
    int w1 = __builtin_amdgcn_cvt_pk_fp8_f32(v1.x, v1.y, 0, false);
    w1     = __builtin_amdgcn_cvt_pk_fp8_f32(v1.z, v1.w, w1, true);
    reinterpret_cast<int2*>(xq + (size_t)row * D)[lane] = make_int2(w0, w1);

    float s = v0.x * v0.x + v0.y * v0.y + v0.z * v0.z + v0.w * v0.w +
              v1.x * v1.x + v1.y * v1.y + v1.z * v1.z + v1.w * v1.w;
    #pragma unroll
    for (int off = 32; off > 0; off >>= 1) s += __shfl_down(s, off);
    if (lane == 0) sq[row] = s;
}

// ---------------------------------------------------------------------------
// Kernel 2, v10 (resubmit; round-9 run died on container acquisition, not
// kernel verdict) = v9 (wave-private staging, zero barriers; fill-normalized
// tie with v4 as best) + ONE change: LDS-TRANSPOSED CONTIGUOUS EPILOGUE.
//
// Rationale: v4 (barrier-synced) == v9 (barrier-free) within noise => the
// K-loop scheduling axis is exhausted. The never-varied pipe is the store
// pattern. C/D layout puts quad on the ROW axis: each store instruction
// writes 4 scattered 64B half-lines on 4 far-apart output rows; full lines
// only form if L2 merges across instructions/waves. v2's NT-store +10us
// proved the store path is merge-sensitive (NT killed merging). Fix: after
// the K-loop the wave's 12KB LDS is dead -- write the 32x64 distance tile
// into it (stride 66 dwords: all LDS ops <=2-way bank conflict = free, m136),
// lgkmcnt(0)+sched_barrier(0) (wave-local, no block barrier), then store
// row-by-row: one instruction = 64 lanes x 4B = 256B CONTIGUOUS row segment
// (2-3 dense adjacent lines). Row offsets are wave-uniform => SGPR-based
// addressing. dwordx4 impossible (triangular rowoff => arbitrary alignment).
// Partial (diagonal) tiles -- 64/4160 -- keep the predicated scalar path.
//
// Tile map: row-group gi (32 rows) has floor(gi/2)+1 col-panels (64 cols).
// Cumulative: C(2a) = a(a+1), C(2a+1) = (a+1)^2. Partial (diagonal) tile
// iff jg == gi>>1.
// ---------------------------------------------------------------------------
__global__ __launch_bounds__(256, 3) void pairdist_kernel(const unsigned char* __restrict__ xq,
                                                          const float* __restrict__ sq,
                                                          float* __restrict__ out) {
    __shared__ __align__(16) unsigned char lds[4][12 * 1024];  // 48 KB

    int tid  = threadIdx.x;
    int w    = tid >> 6;        // wave 0..3 (independent tiles)
    int lane = tid & 63;
    int quad = lane >> 4;       // 0..3
    int lr   = lane & 15;       // 0..15

    int t = blockIdx.x * 4 + w;            // wave-tile id, 0..4159

    // t -> (gi, jg)
    int a = (int)((sqrtf(4.0f * (float)t + 1.0f) - 1.0f) * 0.5f);
    while (a * (a + 1) > t) a--;
    while ((a + 1) * (a + 2) <= t) a++;
    int gi, jg;
    int r0 = t - a * (a + 1);
    if (r0 <= a) { gi = 2 * a;     jg = r0; }
    else         { gi = 2 * a + 1; jg = t - (a + 1) * (a + 1); }
    const bool partial = (jg == (gi >> 1));

    int ibase = gi * WTM;
    int jbase = jg * WTN;

    // Staging geometry: lane l -> row l>>3, LDS chunk l&7; global source
    // chunk = (l&7) ^ (l>>3) (the XOR swizzle). Each glds covers 8 rows =
    // 8 full 128B cache lines.
    int srow   = lane >> 3;
    int schunk = lane & 7;
    int sw     = ((schunk ^ srow) << 4);
    const unsigned char* ga = xq + (size_t)(ibase + srow) * D + sw;
    const unsigned char* gb = xq + (size_t)(jbase + srow) * D + sw;
    unsigned char* la = &lds[w][0];         // 4 KB: A rows ibase..+31
    unsigned char* lb = &lds[w][4 * 1024];  // 8 KB: B rows jbase..+63

    // Fragment read offsets within a row (swizzled).
    const int c0 = (((2 * quad) ^ (lr & 7)) << 4);
    const int c1 = c0 ^ 16;

    f32x4 acc[2][4];
    #pragma unroll
    for (int mt = 0; mt < 2; mt++)
        #pragma unroll
        for (int nt = 0; nt < 4; nt++)
            acc[mt][nt] = (f32x4)0.0f;

    // ---- iter 0 stage issue ----
    #pragma unroll
    for (int g = 0; g < 4; g++)
        __builtin_amdgcn_global_load_lds(
            (const __attribute__((address_space(1))) void*)(ga + (size_t)g * 8 * D),
            (__attribute__((address_space(3))) void*)(la + g * 8 * BK), 16, 0, 0);
    #pragma unroll
    for (int g = 0; g < 8; g++)
        __builtin_amdgcn_global_load_lds(
            (const __attribute__((address_space(1))) void*)(gb + (size_t)g * 8 * D),
            (__attribute__((address_space(3))) void*)(lb + g * 8 * BK), 16, 0, 0);

    // sq preload: latency hides under the stage in flight.
    float sqi[2][4], sqj[4];
    #pragma unroll
    for (int mt = 0; mt < 2; mt++)
        #pragma unroll
        for (int tt = 0; tt < 4; tt++)
            sqi[mt][tt] = sq[ibase + mt * 16 + quad * 4 + tt];
    #pragma unroll
    for (int nt = 0; nt < 4; nt++)
        sqj[nt] = sq[jbase + nt * 16 + lr];

    #pragma unroll
    for (int it = 0; it < KITERS; it++) {
        // Wait for this wave's stage (vmcnt(0); exp=7, lgkm=15: no-wait).
        __builtin_amdgcn_s_waitcnt(0x0F70);
        __builtin_amdgcn_sched_barrier(0);   // no ds_read hoisting above the wait

        i32x8 af[2], bfr[4];
        #pragma unroll
        for (int mt = 0; mt < 2; mt++) {
            const unsigned char* rb = la + (mt * 16 + lr) * BK;
            i32x4 lo = *reinterpret_cast<const i32x4*>(rb + c0);
            i32x4 hi = *reinterpret_cast<const i32x4*>(rb + c1);
            af[mt][0] = lo[0]; af[mt][1] = lo[1]; af[mt][2] = lo[2]; af[mt][3] = lo[3];
            af[mt][4] = hi[0]; af[mt][5] = hi[1]; af[mt][6] = hi[2]; af[mt][7] = hi[3];
        }
        #pragma unroll
        for (int nt = 0; nt < 4; nt++) {
            const unsigned char* rb = lb + (nt * 16 + lr) * BK;
            i32x4 lo = *reinterpret_cast<const i32x4*>(rb + c0);
            i32x4 hi = *reinterpret_cast<const i32x4*>(rb + c1);
            bfr[nt][0] = lo[0]; bfr[nt][1] = lo[1]; bfr[nt][2] = lo[2]; bfr[nt][3] = lo[3];
            bfr[nt][4] = hi[0]; bfr[nt][5] = hi[1]; bfr[nt][6] = hi[2]; bfr[nt][7] = hi[3];
        }

        if (it + 1 < KITERS) {
            // All frag ds_reads must have landed before overwriting the
            // buffer (glds LDS-writes are not ordered vs in-flight ds_read).
            // lgkmcnt(0); vmcnt=63, exp=7: no-wait.
            __builtin_amdgcn_s_waitcnt(0xC07F);
            __builtin_amdgcn_sched_barrier(0);
            const int k0 = (it + 1) * BK;
            #pragma unroll
            for (int g = 0; g < 4; g++)
                __builtin_amdgcn_global_load_lds(
                    (const __attribute__((address_space(1))) void*)(ga + k0 + (size_t)g * 8 * D),
                    (__attribute__((address_space(3))) void*)(la + g * 8 * BK), 16, 0, 0);
            #pragma unroll
            for (int g = 0; g < 8; g++)
                __builtin_amdgcn_global_load_lds(
                    (const __attribute__((address_space(1))) void*)(gb + k0 + (size_t)g * 8 * D),
                    (__attribute__((address_space(3))) void*)(lb + g * 8 * BK), 16, 0, 0);
        }

        #pragma unroll
        for (int mt = 0; mt < 2; mt++)
            #pragma unroll
            for (int nt = 0; nt < 4; nt++)
                acc[mt][nt] = __builtin_amdgcn_mfma_scale_f32_16x16x128_f8f6f4(
                    af[mt], bfr[nt], acc[mt][nt],
                    0, 0,                 // cbsz=0 (A fp8 e4m3), blgp=0 (B fp8 e4m3)
                    0, 0x7F7F7F7F,        // A scale: e8m0 127 = x1.0
                    0, 0x7F7F7F7F);       // B scale: x1.0
    }

    // Epilogue. C/D layout: value (mt,nt,tt) -> row i = ibase+mt*16+quad*4+tt,
    // col j = jbase+nt*16+lr.
    if (!partial) {
        // --- LDS-transposed contiguous stores (full tiles) ---
        // Wave-private transpose buffer: 32 rows x 66 dwords (pad 66 => all
        // LDS writes/reads <=2-way bank conflict = free). 8448 B <= 12 KB
        // (spans la+lb, both dead after the K-loop; ds_write ordering after
        // the final ds_reads is enforced by the acc->MFMA data dependence).
        float* tb = (float*)la;
        #pragma unroll
        for (int mt = 0; mt < 2; mt++) {
            #pragma unroll
            for (int tt = 0; tt < 4; tt++) {
                int row = mt * 16 + quad * 4 + tt;       // 0..31
                #pragma unroll
                for (int nt = 0; nt < 4; nt++) {
                    float d2 = sqi[mt][tt] + sqj[nt] - 2.0f * acc[mt][nt][tt];
                    tb[row * 66 + nt * 16 + lr] = __builtin_amdgcn_sqrtf(fmaxf(d2, 0.0f));
                }
            }
        }
        __builtin_amdgcn_s_waitcnt(0xC07F);   // lgkmcnt(0): transpose written
        __builtin_amdgcn_sched_barrier(0);
        // Row-by-row: one store instruction = 64 lanes x 4B = 256 B
        // contiguous segment of output row i (wave-uniform base => SGPR).
        #pragma unroll
        for (int r = 0; r < 32; r++) {
            int i = ibase + r;                             // wave-uniform
            unsigned rowoff = (unsigned)(i * (i - 1) / 2); // scalar arith
            out[rowoff + (unsigned)(jbase + lane)] = tb[r * 66 + lane];
        }
    } else {
        // --- predicated scalar path (64 diagonal tiles) ---
        #pragma unroll
        for (int mt = 0; mt < 2; mt++) {
            #pragma unroll
            for (int tt = 0; tt < 4; tt++) {
                int i = ibase + mt * 16 + quad * 4 + tt;
                unsigned rowoff = (unsigned)(i * (i - 1) / 2);
                #pragma unroll
                for (int nt = 0; nt < 4; nt++) {
                    int j = jbase + nt * 16 + lr;
                    if (j < i) {
                        float d2 = sqi[mt][tt] + sqj[nt] - 2.0f * acc[mt][nt][tt];
                        out[rowoff + (unsigned)j] = __builtin_amdgcn_sqrtf(fmaxf(d2, 0.0f));
                    }
                }
            }
        }
    }
}

extern "C" void kernel_launch(void* const* d_in, const int* in_sizes, int n_in,
                              void* d_out, int out_size, void* d_ws, size_t ws_size,
                              hipStream_t stream) {
    const float* x = (const float*)d_in[0];
    float* out = (float*)d_out;

    // Workspace layout: [0, 2MB) fp8 copy of x; then 16KB of fp32 row norms.
    unsigned char* xq = (unsigned char*)d_ws;
    float* sq = (float*)((char*)d_ws + (size_t)N * D);

    prep_kernel<<<N / 4, 256, 0, stream>>>(x, xq, sq);

    pairdist_kernel<<<GRID, 256, 0, stream>>>(xq, sq, out);
}